// Round 12
// baseline (480.737 us; speedup 1.0000x reference)
//
#include <hip/hip_runtime.h>
#include <hip/hip_bf16.h>

// Tree-LSTM, depth-15 complete binary tree. N=32767, state 2H=512, gates 2048.
// R14 = R13 (best, 385us) + two changes:
//  1. d11 (B=2048) -> gemm_lstm (512 blocks, 2/CU) instead of big (256, 1/CU).
//  2. d4..d0 fused into ONE tiny_fused kernel (64 blocks, device-scope atomic
//     global barrier, W rows register-cached across all 5 levels). Replaces 10
//     serialized launches; Hsplit writes dropped for d<=4 (no consumer).
// Routing: d13,d12 big_v2 (x-pinned XCD swizzle); d11..d5 gemm_lstm; d4..d0 fused.

#define NNODES 32767

typedef __attribute__((ext_vector_type(8))) short bf16x8;
typedef __attribute__((ext_vector_type(4))) float f32x4;

typedef const __attribute__((address_space(1))) void* gptr_t;
typedef __attribute__((address_space(3))) void* lptr_t;

__device__ __forceinline__ float sigf(float x) { return 1.0f / (1.0f + __expf(-x)); }
__device__ __forceinline__ float tanhfast(float x) { return 2.0f / (1.0f + __expf(-2.0f * x)) - 1.0f; }

__device__ __forceinline__ short bf_hi(float x) {
    __hip_bfloat16 h = __float2bfloat16(x);
    return __builtin_bit_cast(short, h);
}
__device__ __forceinline__ float bf_f(short s) {
    __hip_bfloat16 h = __builtin_bit_cast(__hip_bfloat16, s);
    return __bfloat162float(h);
}
__device__ __forceinline__ void split8(const float* src, short* hi, short* lo) {
#pragma unroll
    for (int j = 0; j < 8; ++j) {
        float x = src[j];
        short h = bf_hi(x);
        hi[j] = h;
        lo[j] = bf_hi(x - bf_f(h));
    }
}

// Device-scope global barrier for co-resident grids (all blocks must be resident).
__device__ __forceinline__ void gbar(int* cnt, int* gen, int nb) {
    __syncthreads();
    __threadfence();  // release: publish this block's writes
    if (threadIdx.x == 0) {
        int g = atomicAdd(gen, 0);
        if (atomicAdd(cnt, 1) == nb - 1) {
            atomicExch(cnt, 0);
            atomicAdd(gen, 1);
        } else {
            while (atomicAdd(gen, 0) == g) { __builtin_amdgcn_s_sleep(8); }
        }
    }
    __syncthreads();
    __threadfence();  // acquire: invalidate stale cached lines before reads
}

// proj[v][r] = dot(emb[v], W_ih[r]) + b_ih[r] + b_hh[r];  grid 256, block 256
// Also re-initializes the tiny_fused barrier variables each run.
__global__ void proj_kernel(const float* __restrict__ emb, const float* __restrict__ W_ih,
                            const float* __restrict__ b_ih, const float* __restrict__ b_hh,
                            float* __restrict__ proj, int* bar) {
    if (blockIdx.x == 0 && threadIdx.x == 0) {
        atomicExch(bar, 0);
        atomicExch(bar + 1, 0);
    }
    __shared__ float e[256];
    int v = blockIdx.x >> 3;
    int rc = blockIdx.x & 7;
    int t = threadIdx.x;
    e[t] = emb[v * 256 + t];
    __syncthreads();
    int r = rc * 256 + t;
    const float4* w4 = (const float4*)(W_ih + (size_t)r * 256);
    const float4* e4 = (const float4*)e;
    float acc = 0.f;
#pragma unroll 8
    for (int k = 0; k < 64; ++k) {
        float4 w = w4[k];
        float4 h = e4[k];
        acc += w.x * h.x + w.y * h.y + w.z * h.z + w.w * h.w;
    }
    proj[v * 2048 + r] = acc + b_ih[r] + b_hh[r];
}

// W_hh [2048][512] fp32 -> MFMA B-fragment bf16 hi/lo tables.  grid 512, block 256
__global__ void wpack_kernel(const float* __restrict__ W_hh,
                             short* __restrict__ Whi, short* __restrict__ Wlo) {
    int t = blockIdx.x * 256 + threadIdx.x;
    int lane = t & 63;
    int kt = (t >> 6) & 15;
    int ntile = t >> 10;
    int n = ntile * 16 + (lane & 15);
    int k0 = kt * 32 + (lane >> 4) * 8;
    const float* src = W_hh + (size_t)n * 512 + k0;
    short hi[8], lo[8];
    split8(src, hi, lo);
    *(bf16x8*)(Whi + (size_t)t * 8) = *(bf16x8*)hi;
    *(bf16x8*)(Wlo + (size_t)t * 8) = *(bf16x8*)lo;
}

// leaves: gates = proj[type]. ONE block per node; grid 16384, block 256.
__global__ void leaf_kernel(const int* __restrict__ types, const float* __restrict__ proj,
                            float* __restrict__ out, float* __restrict__ C256,
                            short* __restrict__ Hsplit) {
    int node = 16383 + blockIdx.x;
    int t = threadIdx.x;
    int tt = types[node];
    const float* p = proj + (size_t)tt * 2048;
    float gi = p[t];
    float gg = p[1024 + t];
    float go = p[1536 + t];
    float cn = sigf(gi) * tanhfast(gg);
    float hn = sigf(go) * tanhfast(cn);
    out[(size_t)node * 512 + t] = hn;
    C256[(size_t)node * 256 + t] = cn;
    short hi = bf_hi(hn);
    Hsplit[(size_t)node * 512 + t] = hi;
    Hsplit[(size_t)node * 512 + 256 + t] = bf_hi(hn - bf_f(hi));
    float gi2 = p[256 + t];
    float gg2 = p[1280 + t];
    float go2 = p[1792 + t];
    float cn2 = sigf(gi2) * tanhfast(gg2);
    float hn2 = sigf(go2) * tanhfast(cn2);
    out[(size_t)node * 512 + 256 + t] = hn2;
}

// ---------------------------------------------------------------------------
// Big levels (B >= 4096): big_v2. 256 thr / 4 waves, tile 128 x 128, BK=32,
// 2 x 32KB LDS dbuf (2 blocks/CU), reformed contiguous A-staging, counted-vmcnt
// 2-barrier pipeline, x-pinned-per-XCD swizzle.
// ---------------------------------------------------------------------------
__global__ __launch_bounds__(256) void big_gemm_lstm_kernel(
    const int* __restrict__ a_idx, const int* __restrict__ b_idx,
    const int* __restrict__ types, float* __restrict__ out,
    const float* __restrict__ proj, float* __restrict__ C256,
    short* __restrict__ Hsplit, int node_base) {
    __shared__ __align__(16) short lds[2][16384];  // 64 KB: 2 x 32 chunks x 512
    __shared__ int sA[128], sB[128], sT[128];

    const unsigned WOFF = 16777216u;  // Whi - Hsplit in shorts (ws layout)

    int t = threadIdx.x;
    int lin = blockIdx.x;
    int xcd = lin & 7;
    int g = lin >> 3;
    int y = g & 15;
    int x = (g >> 4) * 8 + xcd;
    int node0 = node_base + x * 128;
    int j0 = y * 32;

    if (t < 128) {
        sA[t] = a_idx[node0 + t];
        sB[t] = b_idx[node0 + t];
        sT[t] = types[node0 + t];
    }
    __syncthreads();

    int w = t >> 6, lane = t & 63;
    int wm = w >> 1, wn = w & 1;

    unsigned b0[8], b1[8], sk;
    if (w < 2) {
        sk = 32u;
#pragma unroll
        for (int i = 0; i < 8; ++i) {
            int ca = w * 8 + i;
            int rl = lane >> 3;
            int r_loc = ca * 8 + rl;
            int j = (lane & 7) ^ rl;
            unsigned ks = (unsigned)(j >> 2) * 256u + (unsigned)(j & 3) * 8u;
            b0[i] = (unsigned)sA[r_loc] * 512u + ks;
            b1[i] = (unsigned)sB[r_loc] * 512u + ks;
        }
    } else {
        sk = 512u;
#pragma unroll
        for (int i = 0; i < 8; ++i) {
            int cc = (w - 2) * 8 + i;
            int nt = cc >> 1, part = cc & 1;
            int q = nt >> 1, sub = nt & 1;
            unsigned ntg = (unsigned)(q * 32 + y * 2 + sub);
            b0[i] = WOFF + ntg * 8192u + (unsigned)part * 1048576u + (unsigned)lane * 8u;
            b1[i] = b0[i] + 4096u;
        }
    }

    f32x4 acc[4][4];
#pragma unroll
    for (int i = 0; i < 4; ++i)
#pragma unroll
        for (int q = 0; q < 4; ++q) acc[i][q] = (f32x4){0.f, 0.f, 0.f, 0.f};

    auto stage = [&](int kt, int buf) {
#pragma unroll
        for (int i = 0; i < 8; ++i) {
            unsigned off = ((kt < 8) ? b0[i] : b1[i]) + (unsigned)(kt & 7) * sk;
            const short* gsrc = Hsplit + off;
            short* ldst = &lds[buf][(w * 8 + i) * 512];
            __builtin_amdgcn_global_load_lds((gptr_t)gsrc, (lptr_t)ldst, 16, 0, 0);
        }
    };

    auto compute = [&](int buf) {
        const short* L = lds[buf];
        int s = lane >> 4;
        bf16x8 ah[4], al[4];
#pragma unroll
        for (int i = 0; i < 4; ++i) {
            int m_loc = (wm * 4 + i) * 16 + (lane & 15);
            int ch = m_loc >> 3;
            int r = m_loc & 7;
            const short* base = L + ch * 512 + r * 64;
            ah[i] = *(const bf16x8*)&base[(s ^ r) * 8];
            al[i] = *(const bf16x8*)&base[((4 + s) ^ r) * 8];
        }
        __builtin_amdgcn_s_setprio(1);
#pragma unroll
        for (int q = 0; q < 4; ++q) {
            int nt = q * 2 + wn;
            bf16x8 bh = *(const bf16x8*)&L[(16 + nt * 2) * 512 + lane * 8];
            bf16x8 bl = *(const bf16x8*)&L[(17 + nt * 2) * 512 + lane * 8];
#pragma unroll
            for (int i = 0; i < 4; ++i) {
                acc[i][q] = __builtin_amdgcn_mfma_f32_16x16x32_bf16(ah[i], bh, acc[i][q], 0, 0, 0);
                acc[i][q] = __builtin_amdgcn_mfma_f32_16x16x32_bf16(ah[i], bl, acc[i][q], 0, 0, 0);
                acc[i][q] = __builtin_amdgcn_mfma_f32_16x16x32_bf16(al[i], bh, acc[i][q], 0, 0, 0);
            }
        }
        __builtin_amdgcn_s_setprio(0);
    };

    stage(0, 0);
    int cur = 0;
#pragma unroll 1
    for (int kt = 0; kt < 16; ++kt) {
        __builtin_amdgcn_s_barrier();
        if (kt < 15) stage(kt + 1, cur ^ 1);
        if (kt < 15) {
            asm volatile("s_waitcnt vmcnt(8)" ::: "memory");
        } else {
            asm volatile("s_waitcnt vmcnt(0)" ::: "memory");
        }
        __builtin_amdgcn_s_barrier();
        compute(cur);
        cur ^= 1;
    }

    int j = j0 + wn * 16 + (lane & 15);
    bool fh = (j < 256);
    int jc = j & 255;
#pragma unroll
    for (int i = 0; i < 4; ++i) {
        int mrow = wm * 64 + i * 16 + (lane >> 4) * 4;
#pragma unroll
        for (int r = 0; r < 4; ++r) {
            int m_loc = mrow + r;
            int node = node0 + m_loc;
            const float* p = proj + (size_t)sT[m_loc] * 2048 + j;
            float gi = acc[i][0][r] + p[0];
            float gf = acc[i][1][r] + p[512];
            float gg = acc[i][2][r] + p[1024];
            float go = acc[i][3][r] + p[1536];
            int child = fh ? sA[m_loc] : sB[m_loc];
            float c = C256[(size_t)child * 256 + jc];
            float cn = sigf(gf) * c + sigf(gi) * tanhfast(gg);
            float hn = sigf(go) * tanhfast(cn);
            out[(size_t)node * 512 + j] = hn;
            if (fh) {
                C256[(size_t)node * 256 + j] = cn;
                short hi = bf_hi(hn);
                Hsplit[(size_t)node * 512 + j] = hi;
                Hsplit[(size_t)node * 512 + 256 + j] = bf_hi(hn - bf_f(hi));
            }
        }
    }
}

// Fused MFMA GEMM + LSTM (mid levels 32..2048).  32 nodes/block, grid (B/32, J).
__global__ __launch_bounds__(256) void gemm_lstm_kernel(
    const int* __restrict__ a_idx, const int* __restrict__ b_idx,
    const int* __restrict__ types, float* __restrict__ out,
    const short* __restrict__ Whi, const short* __restrict__ Wlo,
    const float* __restrict__ proj, float* __restrict__ C256,
    short* __restrict__ Hsplit, int node_base, int Jc) {
    __shared__ short Ahi[2][16][64][8];   // 32 KB
    __shared__ short Alo[2][16][64][8];   // 32 KB
    __shared__ int sA[32], sB[32], sT[32];
    int t = threadIdx.x;
    int node0 = node_base + blockIdx.x * 32;
    if (t < 32) {
        sA[t] = a_idx[node0 + t];
        sB[t] = b_idx[node0 + t];
        sT[t] = types[node0 + t];
    }
    __syncthreads();

#pragma unroll
    for (int it = 0; it < 8; ++it) {
        int c = it * 256 + t;
        int mt = c >> 10;
        int kt = (c >> 6) & 15;
        int lane = c & 63;
        int m_loc = mt * 16 + (lane & 15);
        int k0 = kt * 32 + (lane >> 4) * 8;
        int child = (k0 < 256) ? sA[m_loc] : sB[m_loc];
        const short* src = Hsplit + (size_t)child * 512 + (k0 & 255);
        *(bf16x8*)&Ahi[mt][kt][lane][0] = *(const bf16x8*)src;
        *(bf16x8*)&Alo[mt][kt][lane][0] = *(const bf16x8*)(src + 256);
    }
    __syncthreads();

    int w = t >> 6;
    int lane = t & 63;
    int jsteps = Jc >> 4;
    int jbase = blockIdx.y * Jc;

    auto epilogue = [&](int j0, f32x4 (&acc)[4][2]) {
        int j = j0 + (lane & 15);
        int jc = j & 255;
        bool fh = (j < 256);
#pragma unroll
        for (int mt = 0; mt < 2; ++mt) {
            int mrow = mt * 16 + (lane >> 4) * 4;
#pragma unroll
            for (int r = 0; r < 4; ++r) {
                int m_loc = mrow + r;
                int node = node0 + m_loc;
                const float* p = proj + (size_t)sT[m_loc] * 2048 + j;
                float gi = acc[0][mt][r] + p[0];
                float gf = acc[1][mt][r] + p[512];
                float gg = acc[2][mt][r] + p[1024];
                float go = acc[3][mt][r] + p[1536];
                int child = fh ? sA[m_loc] : sB[m_loc];
                float c = C256[(size_t)child * 256 + jc];
                float cn = sigf(gf) * c + sigf(gi) * tanhfast(gg);
                float hn = sigf(go) * tanhfast(cn);
                out[(size_t)node * 512 + j] = hn;
                if (fh) {
                    C256[(size_t)node * 256 + j] = cn;
                    short hi = bf_hi(hn);
                    Hsplit[(size_t)node * 512 + j] = hi;
                    Hsplit[(size_t)node * 512 + 256 + j] = bf_hi(hn - bf_f(hi));
                }
            }
        }
    };

    if (jsteps >= 4) {
        for (int js = w; js < jsteps; js += 4) {
            int j0 = jbase + js * 16;
            f32x4 acc[4][2];
#pragma unroll
            for (int q = 0; q < 4; ++q)
#pragma unroll
                for (int mt = 0; mt < 2; ++mt) acc[q][mt] = (f32x4){0.f, 0.f, 0.f, 0.f};
            int nt0 = j0 >> 4;
#pragma unroll 4
            for (int kt = 0; kt < 16; ++kt) {
                bf16x8 ah0 = *(const bf16x8*)&Ahi[0][kt][lane][0];
                bf16x8 al0 = *(const bf16x8*)&Alo[0][kt][lane][0];
                bf16x8 ah1 = *(const bf16x8*)&Ahi[1][kt][lane][0];
                bf16x8 al1 = *(const bf16x8*)&Alo[1][kt][lane][0];
#pragma unroll
                for (int q = 0; q < 4; ++q) {
                    int ntile = q * 32 + nt0;
                    size_t off = ((size_t)(ntile * 16 + kt) * 64 + lane) * 8;
                    bf16x8 bh = *(const bf16x8*)(Whi + off);
                    bf16x8 bl = *(const bf16x8*)(Wlo + off);
                    acc[q][0] = __builtin_amdgcn_mfma_f32_16x16x32_bf16(ah0, bh, acc[q][0], 0, 0, 0);
                    acc[q][0] = __builtin_amdgcn_mfma_f32_16x16x32_bf16(ah0, bl, acc[q][0], 0, 0, 0);
                    acc[q][0] = __builtin_amdgcn_mfma_f32_16x16x32_bf16(al0, bh, acc[q][0], 0, 0, 0);
                    acc[q][1] = __builtin_amdgcn_mfma_f32_16x16x32_bf16(ah1, bh, acc[q][1], 0, 0, 0);
                    acc[q][1] = __builtin_amdgcn_mfma_f32_16x16x32_bf16(ah1, bl, acc[q][1], 0, 0, 0);
                    acc[q][1] = __builtin_amdgcn_mfma_f32_16x16x32_bf16(al1, bh, acc[q][1], 0, 0, 0);
                }
            }
            epilogue(j0, acc);
        }
    } else {
        int js = w & 1;
        int khalf = w >> 1;
        int j0 = jbase + js * 16;
        f32x4 acc[4][2];
#pragma unroll
        for (int q = 0; q < 4; ++q)
#pragma unroll
            for (int mt = 0; mt < 2; ++mt) acc[q][mt] = (f32x4){0.f, 0.f, 0.f, 0.f};
        int nt0 = j0 >> 4;
        int kt0 = khalf * 8;
#pragma unroll 4
        for (int kt = kt0; kt < kt0 + 8; ++kt) {
            bf16x8 ah0 = *(const bf16x8*)&Ahi[0][kt][lane][0];
            bf16x8 al0 = *(const bf16x8*)&Alo[0][kt][lane][0];
            bf16x8 ah1 = *(const bf16x8*)&Ahi[1][kt][lane][0];
            bf16x8 al1 = *(const bf16x8*)&Alo[1][kt][lane][0];
#pragma unroll
            for (int q = 0; q < 4; ++q) {
                int ntile = q * 32 + nt0;
                size_t off = ((size_t)(ntile * 16 + kt) * 64 + lane) * 8;
                bf16x8 bh = *(const bf16x8*)(Whi + off);
                bf16x8 bl = *(const bf16x8*)(Wlo + off);
                acc[q][0] = __builtin_amdgcn_mfma_f32_16x16x32_bf16(ah0, bh, acc[q][0], 0, 0, 0);
                acc[q][0] = __builtin_amdgcn_mfma_f32_16x16x32_bf16(ah0, bl, acc[q][0], 0, 0, 0);
                acc[q][0] = __builtin_amdgcn_mfma_f32_16x16x32_bf16(al0, bh, acc[q][0], 0, 0, 0);
                acc[q][1] = __builtin_amdgcn_mfma_f32_16x16x32_bf16(ah1, bh, acc[q][1], 0, 0, 0);
                acc[q][1] = __builtin_amdgcn_mfma_f32_16x16x32_bf16(ah1, bl, acc[q][1], 0, 0, 0);
                acc[q][1] = __builtin_amdgcn_mfma_f32_16x16x32_bf16(al1, bh, acc[q][1], 0, 0, 0);
            }
        }
        __syncthreads();
        float* xch = (float*)&Ahi[0][0][0][0];
        if (khalf == 1) {
#pragma unroll
            for (int q = 0; q < 4; ++q)
#pragma unroll
                for (int mt = 0; mt < 2; ++mt)
                    *(f32x4*)&xch[(((q * 2 + mt) * 128) + js * 64 + lane) * 4] = acc[q][mt];
        }
        __syncthreads();
        if (khalf == 0) {
#pragma unroll
            for (int q = 0; q < 4; ++q)
#pragma unroll
                for (int mt = 0; mt < 2; ++mt) {
                    f32x4 o = *(const f32x4*)&xch[(((q * 2 + mt) * 128) + js * 64 + lane) * 4];
                    acc[q][mt] += o;
                }
            epilogue(j0, acc);
        }
    }
}

// ---------------------------------------------------------------------------
// Tiny levels (d=4..0, B<=16) in ONE kernel. grid 64 blocks (all co-resident),
// block 256. Block (y=blk>>3, z=blk&7): W rows y*256+t, k-slice z*64..+64,
// register-cached ONCE for all 5 levels. Per level: phase1 = K-split partial
// dots -> part[]; gbar; phase2 (blk < 2B) = combine + LSTM; gbar.
// No Hsplit writes (no consumer at d<=4).
// ---------------------------------------------------------------------------
__global__ __launch_bounds__(256) void tiny_fused_kernel(
    const int* __restrict__ a_idx, const int* __restrict__ b_idx,
    const int* __restrict__ types, const short* __restrict__ Whi,
    const float* __restrict__ proj, float* __restrict__ C256,
    float* __restrict__ out, float* __restrict__ part, int* bar) {
    __shared__ float hs[16][64];   // 4 KB
    const short* Wlo = Whi + 1048576;

    int t = threadIdx.x;
    int blk = blockIdx.x;
    int y = blk >> 3, z = blk & 7;
    int r = y * 256 + t;
    int kbase = z * 64;

    // W row slice -> registers, once for all levels
    float wv[64];
#pragma unroll
    for (int u = 0; u < 8; ++u) {
        int k = kbase + u * 8;
        int kt = k >> 5;
        int sub = (k >> 3) & 3;
        size_t off = ((size_t)((r >> 4) * 16 + kt) * 64 + (sub << 4) + (r & 15)) * 8;
        bf16x8 hi = *(const bf16x8*)(Whi + off);
        bf16x8 lo = *(const bf16x8*)(Wlo + off);
#pragma unroll
        for (int e = 0; e < 8; ++e)
            wv[u * 8 + e] = bf_f(hi[e]) + bf_f(lo[e]);
    }

#pragma unroll 1
    for (int d = 4; d >= 0; --d) {
        int base = (1 << d) - 1;
        int B = 1 << d;
        // phase1: stage h-slices, partial dots -> part
        if (t < B * 16) {
            int n = t >> 4, f4 = t & 15;
            int node = base + n;
            int child = (kbase < 256) ? a_idx[node] : b_idx[node];
            const float* src = out + (size_t)child * 512 + (kbase & 255) + f4 * 4;
            hs[n][f4 * 4 + 0] = src[0];
            hs[n][f4 * 4 + 1] = src[1];
            hs[n][f4 * 4 + 2] = src[2];
            hs[n][f4 * 4 + 3] = src[3];
        }
        __syncthreads();
#pragma unroll 1
        for (int n = 0; n < B; ++n) {
            float acc = 0.f;
#pragma unroll
            for (int k = 0; k < 64; ++k) acc += wv[k] * hs[n][k];
            part[((size_t)z * B + n) * 2048 + r] = acc;
        }
        gbar(bar, bar + 1, 64);
        // phase2: combine + LSTM (blocks 0..2B-1)
        if (blk < 2 * B) {
            int n = blk >> 1;
            int j = ((blk & 1) << 8) + t;
            int node = base + n;
            float g[4] = {0.f, 0.f, 0.f, 0.f};
#pragma unroll 1
            for (int zz = 0; zz < 8; ++zz) {
                const float* p = part + ((size_t)zz * B + n) * 2048;
#pragma unroll
                for (int q = 0; q < 4; ++q) g[q] += p[q * 512 + j];
            }
            const float* p = proj + (size_t)types[node] * 2048 + j;
            float gi = g[0] + p[0];
            float gf = g[1] + p[512];
            float gg = g[2] + p[1024];
            float go = g[3] + p[1536];
            int child = (j < 256) ? a_idx[node] : b_idx[node];
            float c = C256[(size_t)child * 256 + (j & 255)];
            float cn = sigf(gf) * c + sigf(gi) * tanhfast(gg);
            float hn = sigf(go) * tanhfast(cn);
            out[(size_t)node * 512 + j] = hn;
            if (j < 256) C256[(size_t)node * 256 + j] = cn;
        }
        gbar(bar, bar + 1, 64);
    }
}

extern "C" void kernel_launch(void* const* d_in, const int* in_sizes, int n_in,
                              void* d_out, int out_size, void* d_ws, size_t ws_size,
                              hipStream_t stream) {
    const int* types = (const int*)d_in[0];
    const int* a_idx = (const int*)d_in[1];
    const int* b_idx = (const int*)d_in[2];
    const float* emb = (const float*)d_in[3];
    const float* W_ih = (const float*)d_in[4];
    const float* W_hh = (const float*)d_in[5];
    const float* b_ih = (const float*)d_in[6];
    const float* b_hh = (const float*)d_in[7];
    float* out = (float*)d_out;

    float* ws = (float*)d_ws;
    float* proj = ws;                               // 65536 floats (256 KB)
    float* C256 = ws + 65536;                       // 8388352 floats (32 MB)
    short* Hsplit = (short*)(C256 + 8388352);       // 32767*512 shorts (32 MB)
    short* Whi = Hsplit + 16777216;                 // 2048*512 shorts (2 MB); MUST stay
    short* Wlo = Whi + 1048576;                     // contiguous after Hsplit (WOFF)
    float* part = (float*)(Wlo + 1048576);          // 8*16*2048 floats (1 MB)
    int* bar = (int*)(part + 262144);               // 2 ints (barrier cnt/gen)
    // total ws use ~69.3 MB

    proj_kernel<<<256, 256, 0, stream>>>(emb, W_ih, b_ih, b_hh, proj, bar);
    wpack_kernel<<<512, 256, 0, stream>>>(W_hh, Whi, Wlo);
    leaf_kernel<<<16384, 256, 0, stream>>>(types, proj, out, C256, Hsplit);

    for (int d = 13; d >= 5; --d) {
        int base = (1 << d) - 1;
        int B = 1 << d;
        if (B >= 4096) {
            int X = B / 128;
            big_gemm_lstm_kernel<<<X * 16, 256, 0, stream>>>(
                a_idx, b_idx, types, out, proj, C256, Hsplit, base);
        } else {
            int bx = B / 32;
            int J = 2;
            while (bx * J < 512 && J < 16) J <<= 1;
            gemm_lstm_kernel<<<dim3(bx, J), 256, 0, stream>>>(
                a_idx, b_idx, types, out, Whi, Wlo, proj, C256, Hsplit, base, 512 / J);
        }
    }
    tiny_fused_kernel<<<64, 256, 0, stream>>>(
        a_idx, b_idx, types, Whi, proj, C256, out, part, bar);
}

// Round 14
// 387.903 us; speedup vs baseline: 1.2393x; 1.2393x over previous
//
#include <hip/hip_runtime.h>
#include <hip/hip_bf16.h>

// Tree-LSTM, depth-15 complete binary tree. N=32767, state 2H=512, gates 2048.
// R15b = resubmit of R15 (prior bench failed at infra level; all kernels are
// byte-identical to previously-passing ones).
// R15 = R14 minus tiny_fused (software gbar cost ~14us/barrier -> 139us kernel;
// reverted to smallv2+combine pairs), keeping R14's d11->gemm_lstm routing.
// Routing: d13,d12 big_v2 (x-pinned XCD swizzle, counted-vmcnt, reformed
// A-staging); d11..d5 gemm_lstm; d4..d0 smallv2+small_combine. Merged leaf.

#define NNODES 32767

typedef __attribute__((ext_vector_type(8))) short bf16x8;
typedef __attribute__((ext_vector_type(4))) float f32x4;

typedef const __attribute__((address_space(1))) void* gptr_t;
typedef __attribute__((address_space(3))) void* lptr_t;

__device__ __forceinline__ float sigf(float x) { return 1.0f / (1.0f + __expf(-x)); }
__device__ __forceinline__ float tanhfast(float x) { return 2.0f / (1.0f + __expf(-2.0f * x)) - 1.0f; }

__device__ __forceinline__ short bf_hi(float x) {
    __hip_bfloat16 h = __float2bfloat16(x);
    return __builtin_bit_cast(short, h);
}
__device__ __forceinline__ float bf_f(short s) {
    __hip_bfloat16 h = __builtin_bit_cast(__hip_bfloat16, s);
    return __bfloat162float(h);
}
__device__ __forceinline__ void split8(const float* src, short* hi, short* lo) {
#pragma unroll
    for (int j = 0; j < 8; ++j) {
        float x = src[j];
        short h = bf_hi(x);
        hi[j] = h;
        lo[j] = bf_hi(x - bf_f(h));
    }
}

// proj[v][r] = dot(emb[v], W_ih[r]) + b_ih[r] + b_hh[r];  grid 256, block 256
__global__ void proj_kernel(const float* __restrict__ emb, const float* __restrict__ W_ih,
                            const float* __restrict__ b_ih, const float* __restrict__ b_hh,
                            float* __restrict__ proj) {
    __shared__ float e[256];
    int v = blockIdx.x >> 3;
    int rc = blockIdx.x & 7;
    int t = threadIdx.x;
    e[t] = emb[v * 256 + t];
    __syncthreads();
    int r = rc * 256 + t;
    const float4* w4 = (const float4*)(W_ih + (size_t)r * 256);
    const float4* e4 = (const float4*)e;
    float acc = 0.f;
#pragma unroll 8
    for (int k = 0; k < 64; ++k) {
        float4 w = w4[k];
        float4 h = e4[k];
        acc += w.x * h.x + w.y * h.y + w.z * h.z + w.w * h.w;
    }
    proj[v * 2048 + r] = acc + b_ih[r] + b_hh[r];
}

// W_hh [2048][512] fp32 -> MFMA B-fragment bf16 hi/lo tables.  grid 512, block 256
__global__ void wpack_kernel(const float* __restrict__ W_hh,
                             short* __restrict__ Whi, short* __restrict__ Wlo) {
    int t = blockIdx.x * 256 + threadIdx.x;
    int lane = t & 63;
    int kt = (t >> 6) & 15;
    int ntile = t >> 10;
    int n = ntile * 16 + (lane & 15);
    int k0 = kt * 32 + (lane >> 4) * 8;
    const float* src = W_hh + (size_t)n * 512 + k0;
    short hi[8], lo[8];
    split8(src, hi, lo);
    *(bf16x8*)(Whi + (size_t)t * 8) = *(bf16x8*)hi;
    *(bf16x8*)(Wlo + (size_t)t * 8) = *(bf16x8*)lo;
}

// leaves: gates = proj[type]. ONE block per node; grid 16384, block 256.
__global__ void leaf_kernel(const int* __restrict__ types, const float* __restrict__ proj,
                            float* __restrict__ out, float* __restrict__ C256,
                            short* __restrict__ Hsplit) {
    int node = 16383 + blockIdx.x;
    int t = threadIdx.x;
    int tt = types[node];
    const float* p = proj + (size_t)tt * 2048;
    float gi = p[t];
    float gg = p[1024 + t];
    float go = p[1536 + t];
    float cn = sigf(gi) * tanhfast(gg);
    float hn = sigf(go) * tanhfast(cn);
    out[(size_t)node * 512 + t] = hn;
    C256[(size_t)node * 256 + t] = cn;
    short hi = bf_hi(hn);
    Hsplit[(size_t)node * 512 + t] = hi;
    Hsplit[(size_t)node * 512 + 256 + t] = bf_hi(hn - bf_f(hi));
    float gi2 = p[256 + t];
    float gg2 = p[1280 + t];
    float go2 = p[1792 + t];
    float cn2 = sigf(gi2) * tanhfast(gg2);
    float hn2 = sigf(go2) * tanhfast(cn2);
    out[(size_t)node * 512 + 256 + t] = hn2;
}

// ---------------------------------------------------------------------------
// Big levels (B >= 4096): big_v2. 256 thr / 4 waves, tile 128 x 128, BK=32,
// 2 x 32KB LDS dbuf (2 blocks/CU), reformed contiguous A-staging, counted-vmcnt
// 2-barrier pipeline, x-pinned-per-XCD swizzle.
// ---------------------------------------------------------------------------
__global__ __launch_bounds__(256) void big_gemm_lstm_kernel(
    const int* __restrict__ a_idx, const int* __restrict__ b_idx,
    const int* __restrict__ types, float* __restrict__ out,
    const float* __restrict__ proj, float* __restrict__ C256,
    short* __restrict__ Hsplit, int node_base) {
    __shared__ __align__(16) short lds[2][16384];  // 64 KB: 2 x 32 chunks x 512
    __shared__ int sA[128], sB[128], sT[128];

    const unsigned WOFF = 16777216u;  // Whi - Hsplit in shorts (ws layout)

    int t = threadIdx.x;
    int lin = blockIdx.x;
    int xcd = lin & 7;
    int g = lin >> 3;
    int y = g & 15;
    int x = (g >> 4) * 8 + xcd;
    int node0 = node_base + x * 128;
    int j0 = y * 32;

    if (t < 128) {
        sA[t] = a_idx[node0 + t];
        sB[t] = b_idx[node0 + t];
        sT[t] = types[node0 + t];
    }
    __syncthreads();

    int w = t >> 6, lane = t & 63;
    int wm = w >> 1, wn = w & 1;

    unsigned b0[8], b1[8], sk;
    if (w < 2) {
        sk = 32u;
#pragma unroll
        for (int i = 0; i < 8; ++i) {
            int ca = w * 8 + i;
            int rl = lane >> 3;
            int r_loc = ca * 8 + rl;
            int j = (lane & 7) ^ rl;
            unsigned ks = (unsigned)(j >> 2) * 256u + (unsigned)(j & 3) * 8u;
            b0[i] = (unsigned)sA[r_loc] * 512u + ks;
            b1[i] = (unsigned)sB[r_loc] * 512u + ks;
        }
    } else {
        sk = 512u;
#pragma unroll
        for (int i = 0; i < 8; ++i) {
            int cc = (w - 2) * 8 + i;
            int nt = cc >> 1, part = cc & 1;
            int q = nt >> 1, sub = nt & 1;
            unsigned ntg = (unsigned)(q * 32 + y * 2 + sub);
            b0[i] = WOFF + ntg * 8192u + (unsigned)part * 1048576u + (unsigned)lane * 8u;
            b1[i] = b0[i] + 4096u;
        }
    }

    f32x4 acc[4][4];
#pragma unroll
    for (int i = 0; i < 4; ++i)
#pragma unroll
        for (int q = 0; q < 4; ++q) acc[i][q] = (f32x4){0.f, 0.f, 0.f, 0.f};

    auto stage = [&](int kt, int buf) {
#pragma unroll
        for (int i = 0; i < 8; ++i) {
            unsigned off = ((kt < 8) ? b0[i] : b1[i]) + (unsigned)(kt & 7) * sk;
            const short* gsrc = Hsplit + off;
            short* ldst = &lds[buf][(w * 8 + i) * 512];
            __builtin_amdgcn_global_load_lds((gptr_t)gsrc, (lptr_t)ldst, 16, 0, 0);
        }
    };

    auto compute = [&](int buf) {
        const short* L = lds[buf];
        int s = lane >> 4;
        bf16x8 ah[4], al[4];
#pragma unroll
        for (int i = 0; i < 4; ++i) {
            int m_loc = (wm * 4 + i) * 16 + (lane & 15);
            int ch = m_loc >> 3;
            int r = m_loc & 7;
            const short* base = L + ch * 512 + r * 64;
            ah[i] = *(const bf16x8*)&base[(s ^ r) * 8];
            al[i] = *(const bf16x8*)&base[((4 + s) ^ r) * 8];
        }
        __builtin_amdgcn_s_setprio(1);
#pragma unroll
        for (int q = 0; q < 4; ++q) {
            int nt = q * 2 + wn;
            bf16x8 bh = *(const bf16x8*)&L[(16 + nt * 2) * 512 + lane * 8];
            bf16x8 bl = *(const bf16x8*)&L[(17 + nt * 2) * 512 + lane * 8];
#pragma unroll
            for (int i = 0; i < 4; ++i) {
                acc[i][q] = __builtin_amdgcn_mfma_f32_16x16x32_bf16(ah[i], bh, acc[i][q], 0, 0, 0);
                acc[i][q] = __builtin_amdgcn_mfma_f32_16x16x32_bf16(ah[i], bl, acc[i][q], 0, 0, 0);
                acc[i][q] = __builtin_amdgcn_mfma_f32_16x16x32_bf16(al[i], bh, acc[i][q], 0, 0, 0);
            }
        }
        __builtin_amdgcn_s_setprio(0);
    };

    stage(0, 0);
    int cur = 0;
#pragma unroll 1
    for (int kt = 0; kt < 16; ++kt) {
        __builtin_amdgcn_s_barrier();
        if (kt < 15) stage(kt + 1, cur ^ 1);
        if (kt < 15) {
            asm volatile("s_waitcnt vmcnt(8)" ::: "memory");
        } else {
            asm volatile("s_waitcnt vmcnt(0)" ::: "memory");
        }
        __builtin_amdgcn_s_barrier();
        compute(cur);
        cur ^= 1;
    }

    int j = j0 + wn * 16 + (lane & 15);
    bool fh = (j < 256);
    int jc = j & 255;
#pragma unroll
    for (int i = 0; i < 4; ++i) {
        int mrow = wm * 64 + i * 16 + (lane >> 4) * 4;
#pragma unroll
        for (int r = 0; r < 4; ++r) {
            int m_loc = mrow + r;
            int node = node0 + m_loc;
            const float* p = proj + (size_t)sT[m_loc] * 2048 + j;
            float gi = acc[i][0][r] + p[0];
            float gf = acc[i][1][r] + p[512];
            float gg = acc[i][2][r] + p[1024];
            float go = acc[i][3][r] + p[1536];
            int child = fh ? sA[m_loc] : sB[m_loc];
            float c = C256[(size_t)child * 256 + jc];
            float cn = sigf(gf) * c + sigf(gi) * tanhfast(gg);
            float hn = sigf(go) * tanhfast(cn);
            out[(size_t)node * 512 + j] = hn;
            if (fh) {
                C256[(size_t)node * 256 + j] = cn;
                short hi = bf_hi(hn);
                Hsplit[(size_t)node * 512 + j] = hi;
                Hsplit[(size_t)node * 512 + 256 + j] = bf_hi(hn - bf_f(hi));
            }
        }
    }
}

// Fused MFMA GEMM + LSTM (mid levels 32..2048).  32 nodes/block, grid (B/32, J).
__global__ __launch_bounds__(256) void gemm_lstm_kernel(
    const int* __restrict__ a_idx, const int* __restrict__ b_idx,
    const int* __restrict__ types, float* __restrict__ out,
    const short* __restrict__ Whi, const short* __restrict__ Wlo,
    const float* __restrict__ proj, float* __restrict__ C256,
    short* __restrict__ Hsplit, int node_base, int Jc) {
    __shared__ short Ahi[2][16][64][8];   // 32 KB
    __shared__ short Alo[2][16][64][8];   // 32 KB
    __shared__ int sA[32], sB[32], sT[32];
    int t = threadIdx.x;
    int node0 = node_base + blockIdx.x * 32;
    if (t < 32) {
        sA[t] = a_idx[node0 + t];
        sB[t] = b_idx[node0 + t];
        sT[t] = types[node0 + t];
    }
    __syncthreads();

#pragma unroll
    for (int it = 0; it < 8; ++it) {
        int c = it * 256 + t;
        int mt = c >> 10;
        int kt = (c >> 6) & 15;
        int lane = c & 63;
        int m_loc = mt * 16 + (lane & 15);
        int k0 = kt * 32 + (lane >> 4) * 8;
        int child = (k0 < 256) ? sA[m_loc] : sB[m_loc];
        const short* src = Hsplit + (size_t)child * 512 + (k0 & 255);
        *(bf16x8*)&Ahi[mt][kt][lane][0] = *(const bf16x8*)src;
        *(bf16x8*)&Alo[mt][kt][lane][0] = *(const bf16x8*)(src + 256);
    }
    __syncthreads();

    int w = t >> 6;
    int lane = t & 63;
    int jsteps = Jc >> 4;
    int jbase = blockIdx.y * Jc;

    auto epilogue = [&](int j0, f32x4 (&acc)[4][2]) {
        int j = j0 + (lane & 15);
        int jc = j & 255;
        bool fh = (j < 256);
#pragma unroll
        for (int mt = 0; mt < 2; ++mt) {
            int mrow = mt * 16 + (lane >> 4) * 4;
#pragma unroll
            for (int r = 0; r < 4; ++r) {
                int m_loc = mrow + r;
                int node = node0 + m_loc;
                const float* p = proj + (size_t)sT[m_loc] * 2048 + j;
                float gi = acc[0][mt][r] + p[0];
                float gf = acc[1][mt][r] + p[512];
                float gg = acc[2][mt][r] + p[1024];
                float go = acc[3][mt][r] + p[1536];
                int child = fh ? sA[m_loc] : sB[m_loc];
                float c = C256[(size_t)child * 256 + jc];
                float cn = sigf(gf) * c + sigf(gi) * tanhfast(gg);
                float hn = sigf(go) * tanhfast(cn);
                out[(size_t)node * 512 + j] = hn;
                if (fh) {
                    C256[(size_t)node * 256 + j] = cn;
                    short hi = bf_hi(hn);
                    Hsplit[(size_t)node * 512 + j] = hi;
                    Hsplit[(size_t)node * 512 + 256 + j] = bf_hi(hn - bf_f(hi));
                }
            }
        }
    };

    if (jsteps >= 4) {
        for (int js = w; js < jsteps; js += 4) {
            int j0 = jbase + js * 16;
            f32x4 acc[4][2];
#pragma unroll
            for (int q = 0; q < 4; ++q)
#pragma unroll
                for (int mt = 0; mt < 2; ++mt) acc[q][mt] = (f32x4){0.f, 0.f, 0.f, 0.f};
            int nt0 = j0 >> 4;
#pragma unroll 4
            for (int kt = 0; kt < 16; ++kt) {
                bf16x8 ah0 = *(const bf16x8*)&Ahi[0][kt][lane][0];
                bf16x8 al0 = *(const bf16x8*)&Alo[0][kt][lane][0];
                bf16x8 ah1 = *(const bf16x8*)&Ahi[1][kt][lane][0];
                bf16x8 al1 = *(const bf16x8*)&Alo[1][kt][lane][0];
#pragma unroll
                for (int q = 0; q < 4; ++q) {
                    int ntile = q * 32 + nt0;
                    size_t off = ((size_t)(ntile * 16 + kt) * 64 + lane) * 8;
                    bf16x8 bh = *(const bf16x8*)(Whi + off);
                    bf16x8 bl = *(const bf16x8*)(Wlo + off);
                    acc[q][0] = __builtin_amdgcn_mfma_f32_16x16x32_bf16(ah0, bh, acc[q][0], 0, 0, 0);
                    acc[q][0] = __builtin_amdgcn_mfma_f32_16x16x32_bf16(ah0, bl, acc[q][0], 0, 0, 0);
                    acc[q][0] = __builtin_amdgcn_mfma_f32_16x16x32_bf16(al0, bh, acc[q][0], 0, 0, 0);
                    acc[q][1] = __builtin_amdgcn_mfma_f32_16x16x32_bf16(ah1, bh, acc[q][1], 0, 0, 0);
                    acc[q][1] = __builtin_amdgcn_mfma_f32_16x16x32_bf16(ah1, bl, acc[q][1], 0, 0, 0);
                    acc[q][1] = __builtin_amdgcn_mfma_f32_16x16x32_bf16(al1, bh, acc[q][1], 0, 0, 0);
                }
            }
            epilogue(j0, acc);
        }
    } else {
        int js = w & 1;
        int khalf = w >> 1;
        int j0 = jbase + js * 16;
        f32x4 acc[4][2];
#pragma unroll
        for (int q = 0; q < 4; ++q)
#pragma unroll
            for (int mt = 0; mt < 2; ++mt) acc[q][mt] = (f32x4){0.f, 0.f, 0.f, 0.f};
        int nt0 = j0 >> 4;
        int kt0 = khalf * 8;
#pragma unroll 4
        for (int kt = kt0; kt < kt0 + 8; ++kt) {
            bf16x8 ah0 = *(const bf16x8*)&Ahi[0][kt][lane][0];
            bf16x8 al0 = *(const bf16x8*)&Alo[0][kt][lane][0];
            bf16x8 ah1 = *(const bf16x8*)&Ahi[1][kt][lane][0];
            bf16x8 al1 = *(const bf16x8*)&Alo[1][kt][lane][0];
#pragma unroll
            for (int q = 0; q < 4; ++q) {
                int ntile = q * 32 + nt0;
                size_t off = ((size_t)(ntile * 16 + kt) * 64 + lane) * 8;
                bf16x8 bh = *(const bf16x8*)(Whi + off);
                bf16x8 bl = *(const bf16x8*)(Wlo + off);
                acc[q][0] = __builtin_amdgcn_mfma_f32_16x16x32_bf16(ah0, bh, acc[q][0], 0, 0, 0);
                acc[q][0] = __builtin_amdgcn_mfma_f32_16x16x32_bf16(ah0, bl, acc[q][0], 0, 0, 0);
                acc[q][0] = __builtin_amdgcn_mfma_f32_16x16x32_bf16(al0, bh, acc[q][0], 0, 0, 0);
                acc[q][1] = __builtin_amdgcn_mfma_f32_16x16x32_bf16(ah1, bh, acc[q][1], 0, 0, 0);
                acc[q][1] = __builtin_amdgcn_mfma_f32_16x16x32_bf16(ah1, bl, acc[q][1], 0, 0, 0);
                acc[q][1] = __builtin_amdgcn_mfma_f32_16x16x32_bf16(al1, bh, acc[q][1], 0, 0, 0);
            }
        }
        __syncthreads();
        float* xch = (float*)&Ahi[0][0][0][0];
        if (khalf == 1) {
#pragma unroll
            for (int q = 0; q < 4; ++q)
#pragma unroll
                for (int mt = 0; mt < 2; ++mt)
                    *(f32x4*)&xch[(((q * 2 + mt) * 128) + js * 64 + lane) * 4] = acc[q][mt];
        }
        __syncthreads();
        if (khalf == 0) {
#pragma unroll
            for (int q = 0; q < 4; ++q)
#pragma unroll
                for (int mt = 0; mt < 2; ++mt) {
                    f32x4 o = *(const f32x4*)&xch[(((q * 2 + mt) * 128) + js * 64 + lane) * 4];
                    acc[q][mt] += o;
                }
            epilogue(j0, acc);
        }
    }
}

// ---------------------------------------------------------------------------
// Small levels (B <= 16): smallv2 (W read once per level from packed tables).
// grid (8 y, 8 z), block 256.
// ---------------------------------------------------------------------------
__global__ __launch_bounds__(256) void smallv2_gemm_kernel(
    const int* __restrict__ a_idx, const int* __restrict__ b_idx,
    const float* __restrict__ out, const short* __restrict__ Whi,
    float* __restrict__ part, int node_base, int B) {
    __shared__ float hs[16][64];   // 4 KB
    const short* Wlo = Whi + 1048576;

    int t = threadIdx.x;
    int y = blockIdx.x, z = blockIdx.y;
    int r = y * 256 + t;
    int kbase = z * 64;

    if (t < B * 16) {
        int n = t >> 4;
        int f4 = t & 15;
        int node = node_base + n;
        int child = (kbase < 256) ? a_idx[node] : b_idx[node];
        float4 v = ((const float4*)(out + (size_t)child * 512 + (kbase & 255)))[f4];
        *(float4*)&hs[n][f4 * 4] = v;
    }
    __syncthreads();

    float wv[64];
#pragma unroll
    for (int u = 0; u < 8; ++u) {
        int k = kbase + u * 8;
        int kt = k >> 5;
        int sub = (k >> 3) & 3;
        size_t off = ((size_t)((r >> 4) * 16 + kt) * 64 + (sub << 4) + (r & 15)) * 8;
        bf16x8 hi = *(const bf16x8*)(Whi + off);
        bf16x8 lo = *(const bf16x8*)(Wlo + off);
#pragma unroll
        for (int e = 0; e < 8; ++e)
            wv[u * 8 + e] = bf_f(hi[e]) + bf_f(lo[e]);
    }

    for (int n = 0; n < B; ++n) {
        float acc = 0.f;
#pragma unroll
        for (int k = 0; k < 64; ++k) acc += wv[k] * hs[n][k];
        part[((size_t)z * B + n) * 2048 + r] = acc;
    }
}

// combine K-partials + LSTM.  grid (B*2), block 256
__global__ void small_combine_kernel(
    const int* __restrict__ a_idx, const int* __restrict__ b_idx,
    const int* __restrict__ types, const float* __restrict__ part,
    const float* __restrict__ proj, float* __restrict__ C256,
    short* __restrict__ Hsplit, float* __restrict__ out, int node_base, int B) {
    int bi = blockIdx.x;
    int n = bi >> 1;
    int j = ((bi & 1) << 8) + threadIdx.x;
    int node = node_base + n;
    float g[4] = {0.f, 0.f, 0.f, 0.f};
    for (int z = 0; z < 8; ++z) {
        const float* p = part + ((size_t)z * B + n) * 2048;
#pragma unroll
        for (int q = 0; q < 4; ++q) g[q] += p[q * 512 + j];
    }
    const float* p = proj + (size_t)types[node] * 2048 + j;
    float gi = g[0] + p[0];
    float gf = g[1] + p[512];
    float gg = g[2] + p[1024];
    float go = g[3] + p[1536];
    int child = (j < 256) ? a_idx[node] : b_idx[node];
    float c = C256[(size_t)child * 256 + (j & 255)];
    float cn = sigf(gf) * c + sigf(gi) * tanhfast(gg);
    float hn = sigf(go) * tanhfast(cn);
    out[(size_t)node * 512 + j] = hn;
    if (j < 256) {
        C256[(size_t)node * 256 + j] = cn;
        short hi = bf_hi(hn);
        Hsplit[(size_t)node * 512 + j] = hi;
        Hsplit[(size_t)node * 512 + 256 + j] = bf_hi(hn - bf_f(hi));
    }
}

extern "C" void kernel_launch(void* const* d_in, const int* in_sizes, int n_in,
                              void* d_out, int out_size, void* d_ws, size_t ws_size,
                              hipStream_t stream) {
    const int* types = (const int*)d_in[0];
    const int* a_idx = (const int*)d_in[1];
    const int* b_idx = (const int*)d_in[2];
    const float* emb = (const float*)d_in[3];
    const float* W_ih = (const float*)d_in[4];
    const float* W_hh = (const float*)d_in[5];
    const float* b_ih = (const float*)d_in[6];
    const float* b_hh = (const float*)d_in[7];
    float* out = (float*)d_out;

    float* ws = (float*)d_ws;
    float* proj = ws;                               // 65536 floats (256 KB)
    float* C256 = ws + 65536;                       // 8388352 floats (32 MB)
    short* Hsplit = (short*)(C256 + 8388352);       // 32767*512 shorts (32 MB)
    short* Whi = Hsplit + 16777216;                 // 2048*512 shorts (2 MB); MUST stay
    short* Wlo = Whi + 1048576;                     // contiguous after Hsplit (WOFF)
    float* part = (float*)(Wlo + 1048576);          // 8*16*2048 floats (1 MB)
    // total ws use ~69.3 MB

    proj_kernel<<<256, 256, 0, stream>>>(emb, W_ih, b_ih, b_hh, proj);
    wpack_kernel<<<512, 256, 0, stream>>>(W_hh, Whi, Wlo);
    leaf_kernel<<<16384, 256, 0, stream>>>(types, proj, out, C256, Hsplit);

    for (int d = 13; d >= 0; --d) {
        int base = (1 << d) - 1;
        int B = 1 << d;
        if (B >= 4096) {
            int X = B / 128;
            big_gemm_lstm_kernel<<<X * 16, 256, 0, stream>>>(
                a_idx, b_idx, types, out, proj, C256, Hsplit, base);
        } else if (B >= 32) {
            int bx = B / 32;
            int J = 2;
            while (bx * J < 512 && J < 16) J <<= 1;
            gemm_lstm_kernel<<<dim3(bx, J), 256, 0, stream>>>(
                a_idx, b_idx, types, out, Whi, Wlo, proj, C256, Hsplit, base, 512 / J);
        } else {
            smallv2_gemm_kernel<<<dim3(8, 8), 256, 0, stream>>>(
                a_idx, b_idx, out, Whi, part, base, B);
            small_combine_kernel<<<B * 2, 256, 0, stream>>>(
                a_idx, b_idx, types, part, proj, C256, Hsplit, out, base, B);
        }
    }
}